// Round 2
// baseline (1003.826 us; speedup 1.0000x reference)
//
#include <hip/hip_runtime.h>
#include <hip/hip_bf16.h>

typedef __attribute__((ext_vector_type(8))) short bf16x8;
typedef __attribute__((ext_vector_type(4))) float f32x4;
typedef __attribute__((ext_vector_type(4))) unsigned short u16x4;

#define BB 4
#define SS 2048
#define DD 2048
#define HH 16
#define HDD 128
// QK buffer: [B*S][4096] bf16 (Q cols 0..2047, K cols 2048..4095)
// Vt buffer: [B*H][128][2048] bf16 (V transposed: hd-major, s contiguous)

__device__ __forceinline__ unsigned short f2bf(float f) {
  __hip_bfloat16 b = __float2bfloat16(f);
  return *reinterpret_cast<unsigned short*>(&b);
}
__device__ __forceinline__ float bf2f(short u) {
  unsigned short t = (unsigned short)u;
  __hip_bfloat16 b = *reinterpret_cast<__hip_bfloat16*>(&t);
  return __bfloat162float(b);
}
__device__ __forceinline__ void gl_lds16(const void* g, void* l) {
  __builtin_amdgcn_global_load_lds((const __attribute__((address_space(1))) unsigned int*)g,
                                   (__attribute__((address_space(3))) unsigned int*)l, 16, 0, 0);
}

// ---------------- fp32 -> bf16 conversion (vectorized) ----------------
__global__ __launch_bounds__(256) void convertk(const float* __restrict__ src,
                                                __hip_bfloat16* __restrict__ dst, int n4) {
  int i = blockIdx.x * 256 + threadIdx.x;
  if (i >= n4) return;
  f32x4 v = ((const f32x4*)src)[i];
  u16x4 o;
  o[0] = f2bf(v[0]); o[1] = f2bf(v[1]); o[2] = f2bf(v[2]); o[3] = f2bf(v[3]);
  ((u16x4*)dst)[i] = o;
}

// ---------------- B^T GEMM: C[m][n] = sum_k A[m][k] * Bw[n][k] ----------------
template <int MODE>
__global__ __launch_bounds__(256) void gemm_bt(const __hip_bfloat16* __restrict__ A,
                                               const __hip_bfloat16* __restrict__ Bw,
                                               __hip_bfloat16* __restrict__ Cbf,
                                               __hip_bfloat16* __restrict__ Vt,
                                               float* __restrict__ Cf,
                                               int M, int N, int K) {
  __shared__ __hip_bfloat16 As[128 * 32];
  __shared__ __hip_bfloat16 Bs[128 * 32];
  const int tid = threadIdx.x;
  const int wave = tid >> 6, lane = tid & 63;
  const int l15 = lane & 15, l4 = lane >> 4;
  const int bm = blockIdx.x, bn = blockIdx.y;
  const int wr = (wave >> 1) * 64, wc = (wave & 1) * 64;

  const long arow = (long)(bm * 128 + (tid >> 2)) * K + (tid & 3) * 8;
  const long brow = (long)(bn * 128 + (tid >> 2)) * K + (tid & 3) * 8;

  f32x4 acc[4][4] = {};

  for (int k0 = 0; k0 < K; k0 += 32) {
    const __hip_bfloat16* ga = A + arow + k0;
    const __hip_bfloat16* gb = Bw + brow + k0;
    gl_lds16(ga, As + tid * 8);
    gl_lds16(ga + (long)64 * K, As + 2048 + tid * 8);
    gl_lds16(gb, Bs + tid * 8);
    gl_lds16(gb + (long)64 * K, Bs + 2048 + tid * 8);
    __syncthreads();

    bf16x8 af[4], bg[4];
#pragma unroll
    for (int i = 0; i < 4; i++) {
      af[i] = *(const bf16x8*)(As + (wr + i * 16 + l15) * 32 + l4 * 8);
      bg[i] = *(const bf16x8*)(Bs + (wc + i * 16 + l15) * 32 + l4 * 8);
    }
#pragma unroll
    for (int mi = 0; mi < 4; mi++)
#pragma unroll
      for (int nj = 0; nj < 4; nj++)
        acc[mi][nj] = __builtin_amdgcn_mfma_f32_16x16x32_bf16(af[mi], bg[nj], acc[mi][nj], 0, 0, 0);
    __syncthreads();
  }

  if (MODE == 0) {
    if (bn * 128 < 4096) {
#pragma unroll
      for (int mi = 0; mi < 4; mi++)
#pragma unroll
        for (int nj = 0; nj < 4; nj++) {
          int n = bn * 128 + wc + nj * 16 + l15;
#pragma unroll
          for (int r = 0; r < 4; r++) {
            int m = bm * 128 + wr + mi * 16 + l4 * 4 + r;
            Cbf[(long)m * 4096 + n] = __float2bfloat16(acc[mi][nj][r]);
          }
        }
    } else {
#pragma unroll
      for (int mi = 0; mi < 4; mi++)
#pragma unroll
        for (int nj = 0; nj < 4; nj++) {
          int e = bn * 128 + wc + nj * 16 + l15 - 4096;
          int hh = e >> 7, hd = e & 127;
          int m0 = bm * 128 + wr + mi * 16 + l4 * 4;
          int b = m0 >> 11, s0 = m0 & (SS - 1);
          u16x4 pk;
#pragma unroll
          for (int r = 0; r < 4; r++) pk[r] = f2bf(acc[mi][nj][r]);
          *(u16x4*)(Vt + (((long)(b * HH + hh) * 128 + hd) * SS + s0)) = pk;
        }
    }
  } else {
#pragma unroll
    for (int mi = 0; mi < 4; mi++)
#pragma unroll
      for (int nj = 0; nj < 4; nj++) {
        int n = bn * 128 + wc + nj * 16 + l15;
#pragma unroll
        for (int r = 0; r < 4; r++) {
          int m = bm * 128 + wr + mi * 16 + l4 * 4 + r;
          Cf[(long)m * N + n] = acc[mi][nj][r];
        }
      }
  }
}

// ---------------- RoPE on Q and K (in place, bf16x8 = 4 pairs) ----------------
__global__ __launch_bounds__(256) void rope_k(__hip_bfloat16* __restrict__ qkbuf,
                                              const float* __restrict__ fc,
                                              const float* __restrict__ fs,
                                              const int* __restrict__ posp) {
  const int pos = *posp;
  int g = blockIdx.x * 256 + threadIdx.x;
  int i4 = g & 15;
  int h = (g >> 4) & 15;
  int m = g >> 8;
  int s = m & (SS - 1);
  long base = (long)m * 4096 + h * 128 + i4 * 8;
  bf16x8 q = *(bf16x8*)(qkbuf + base);
  bf16x8 k = *(bf16x8*)(qkbuf + base + 2048);
  f32x4 c = *(const f32x4*)(fc + (long)(pos + s) * 64 + i4 * 4);
  f32x4 sn = *(const f32x4*)(fs + (long)(pos + s) * 64 + i4 * 4);
  bf16x8 qo, ko;
#pragma unroll
  for (int j = 0; j < 4; j++) {
    float cj = c[j], sj = sn[j];
    float q0 = bf2f(q[2 * j]), q1 = bf2f(q[2 * j + 1]);
    float k0 = bf2f(k[2 * j]), k1 = bf2f(k[2 * j + 1]);
    qo[2 * j] = (short)f2bf(q0 * cj - q1 * sj);
    qo[2 * j + 1] = (short)f2bf(q0 * sj + q1 * cj);
    ko[2 * j] = (short)f2bf(k0 * cj - k1 * sj);
    ko[2 * j + 1] = (short)f2bf(k0 * sj + k1 * cj);
  }
  *(bf16x8*)(qkbuf + base) = qo;
  *(bf16x8*)(qkbuf + base + 2048) = ko;
}

// ---------------- causal flash attention (balanced + double-buffered) ----------------
// 512 blocks (8 q-pairs x 64 bh, XCD-swizzled); each block does q-tiles qp and 15-qp
// (equal 34 KV tiles per block). 4 waves x 32 q-rows; KVBLK=64; LDS double-buffered;
// async stage split; defer-max; exp2-domain softmax.
__global__ __launch_bounds__(256, 2) void attn_k(const __hip_bfloat16* __restrict__ qk,
                                                 const __hip_bfloat16* __restrict__ vt,
                                                 __hip_bfloat16* __restrict__ aout,
                                                 const int* __restrict__ posp) {
  __shared__ __hip_bfloat16 Ks[2][64 * 128];   // [key][hd], XOR-swizzled
  __shared__ __hip_bfloat16 Vs[2][128 * 64];   // [hd][kv] (V^T), XOR-swizzled
  __shared__ __hip_bfloat16 Ps[4][32 * 64];    // per-wave P, XOR-swizzled
  const int pos = *posp;
  const int orig = blockIdx.x;                  // 512 blocks
  const int swz = (orig & 7) * 64 + (orig >> 3);  // XCD-contiguous
  const int qp = swz & 7, bh = swz >> 3;
  const int b = bh >> 4, h = bh & 15;
  const int tid = threadIdx.x;
  const int wave = tid >> 6, lane = tid & 63;
  const int l15 = lane & 15, l4 = lane >> 4;

  const long kbase = ((long)b * SS) * 4096 + 2048 + h * 128;
  const long vbase = ((long)bh * 128) * SS;
  const float sc2 = 0.08838834764831845f * 1.4426950408889634f;  // 1/sqrt(128) * log2(e)

  // staging decode (constant per thread)
  const int s_kr[4] = {(0 * 256 + tid) >> 4, (1 * 256 + tid) >> 4, (2 * 256 + tid) >> 4, (3 * 256 + tid) >> 4};
  const int s_kc = tid & 15;
  const int s_hd[4] = {(0 * 256 + tid) >> 3, (1 * 256 + tid) >> 3, (2 * 256 + tid) >> 3, (3 * 256 + tid) >> 3};
  const int s_vc = tid & 7;

  bf16x8 kreg[4], vreg[4];

#define LOADKV(T)                                                                             \
  {                                                                                           \
    const int kv0_ = (T) * 64;                                                                \
    _Pragma("unroll") for (int i = 0; i < 4; i++) {                                           \
      kreg[i] = *(const bf16x8*)(qk + kbase + (long)(kv0_ + s_kr[i]) * 4096 + s_kc * 8);      \
      vreg[i] = *(const bf16x8*)(vt + vbase + (long)s_hd[i] * SS + kv0_ + s_vc * 8);          \
    }                                                                                         \
  }

#define STAGE(BI)                                                                             \
  {                                                                                           \
    _Pragma("unroll") for (int i = 0; i < 4; i++) {                                           \
      *(bf16x8*)(Ks[BI] + ((s_kr[i] * 128 + s_kc * 8) ^ ((s_kr[i] & 7) << 3))) = kreg[i];     \
      *(bf16x8*)(Vs[BI] + ((s_hd[i] * 64 + s_vc * 8) ^ ((s_hd[i] & 7) << 3))) = vreg[i];      \
    }                                                                                         \
  }

  for (int half = 0; half < 2; ++half) {
    const int qb = half ? (15 - qp) : qp;
    const int qwb = qb * 128 + wave * 32;

    // Q fragments in registers
    bf16x8 qf[2][4];
#pragma unroll
    for (int mi = 0; mi < 2; mi++)
#pragma unroll
      for (int kk = 0; kk < 4; kk++) {
        long row = (long)b * SS + qwb + mi * 16 + l15;
        qf[mi][kk] = *(const bf16x8*)(qk + row * 4096 + h * 128 + kk * 32 + l4 * 8);
      }

    f32x4 accO[2][8] = {};
    float mrun[2][4], lrun[2][4];
#pragma unroll
    for (int mi = 0; mi < 2; mi++)
#pragma unroll
      for (int r = 0; r < 4; r++) { mrun[mi][r] = -1e30f; lrun[mi][r] = 0.f; }

    int ntiles = (pos + qb * 128 + 127) / 64 + 1;
    if (ntiles > SS / 64) ntiles = SS / 64;

    LOADKV(0);
    __syncthreads();   // protect buf0 from previous half's last compute
    STAGE(0);

    for (int t = 0; t < ntiles; ++t) {
      const int kv0 = t * 64;
      const int cur = t & 1;
      if (t + 1 < ntiles) LOADKV(t + 1);   // async: in flight across barrier+compute
      __syncthreads();                      // staged tile t visible

      // ---- S = Q K^T ----
      f32x4 sfr[2][4] = {};
      __builtin_amdgcn_s_setprio(1);
#pragma unroll
      for (int ni = 0; ni < 4; ni++) {
        const int key = ni * 16 + l15;
        const int sw = (key & 7) << 3;
        bf16x8 kf[4];
#pragma unroll
        for (int kk = 0; kk < 4; kk++)
          kf[kk] = *(const bf16x8*)(Ks[cur] + ((key * 128 + kk * 32 + l4 * 8) ^ sw));
#pragma unroll
        for (int mi = 0; mi < 2; mi++)
#pragma unroll
          for (int kk = 0; kk < 4; kk++)
            sfr[mi][ni] = __builtin_amdgcn_mfma_f32_16x16x32_bf16(qf[mi][kk], kf[kk], sfr[mi][ni], 0, 0, 0);
      }
      __builtin_amdgcn_s_setprio(0);

      // ---- scale (log2 domain) + causal mask ----
      const bool needmask = (kv0 + 63) > (pos + qb * 128);
#pragma unroll
      for (int mi = 0; mi < 2; mi++)
#pragma unroll
        for (int ni = 0; ni < 4; ni++)
#pragma unroll
          for (int r = 0; r < 4; r++) {
            float v = sfr[mi][ni][r] * sc2;
            if (needmask) {
              int key = kv0 + ni * 16 + l15;
              int q = qwb + mi * 16 + l4 * 4 + r;
              if (key > pos + q) v = -1e30f;
            }
            sfr[mi][ni][r] = v;
          }

      // ---- online softmax with defer-max ----
#pragma unroll
      for (int mi = 0; mi < 2; mi++) {
        f32x4 mx = sfr[mi][0];
#pragma unroll
        for (int ni = 1; ni < 4; ni++)
#pragma unroll
          for (int r = 0; r < 4; r++) mx[r] = fmaxf(mx[r], sfr[mi][ni][r]);
#pragma unroll
        for (int d = 1; d < 16; d <<= 1)
#pragma unroll
          for (int r = 0; r < 4; r++) mx[r] = fmaxf(mx[r], __shfl_xor(mx[r], d, 64));

        float growth = mx[0] - mrun[mi][0];
#pragma unroll
        for (int r = 1; r < 4; r++) growth = fmaxf(growth, mx[r] - mrun[mi][r]);
        if (!__all(growth <= 11.0f)) {
          float scal[4];
#pragma unroll
          for (int r = 0; r < 4; r++) {
            float mn = fmaxf(mrun[mi][r], mx[r]);
            scal[r] = exp2f(mrun[mi][r] - mn);
            mrun[mi][r] = mn;
            lrun[mi][r] *= scal[r];
          }
#pragma unroll
          for (int ni = 0; ni < 8; ni++)
#pragma unroll
            for (int r = 0; r < 4; r++) accO[mi][ni][r] *= scal[r];
        }

        f32x4 rs = {0.f, 0.f, 0.f, 0.f};
#pragma unroll
        for (int ni = 0; ni < 4; ni++)
#pragma unroll
          for (int r = 0; r < 4; r++) {
            float p = exp2f(sfr[mi][ni][r] - mrun[mi][r]);
            rs[r] += p;
            int prow = mi * 16 + l4 * 4 + r;
            Ps[wave][(prow * 64 + ni * 16 + l15) ^ ((prow & 7) << 3)] = __float2bfloat16(p);
          }
#pragma unroll
        for (int d = 1; d < 16; d <<= 1)
#pragma unroll
          for (int r = 0; r < 4; r++) rs[r] += __shfl_xor(rs[r], d, 64);
#pragma unroll
        for (int r = 0; r < 4; r++) lrun[mi][r] += rs[r];
      }

      // ---- O += P * V ----
      __builtin_amdgcn_s_setprio(1);
#pragma unroll
      for (int kk = 0; kk < 2; kk++) {
        bf16x8 pf[2];
#pragma unroll
        for (int mi = 0; mi < 2; mi++) {
          int prow = mi * 16 + l15;
          pf[mi] = *(const bf16x8*)(Ps[wave] + ((prow * 64 + kk * 32 + l4 * 8) ^ ((prow & 7) << 3)));
        }
#pragma unroll
        for (int ni = 0; ni < 8; ni++) {
          int hd = ni * 16 + l15;
          bf16x8 vf = *(const bf16x8*)(Vs[cur] + ((hd * 64 + kk * 32 + l4 * 8) ^ ((hd & 7) << 3)));
#pragma unroll
          for (int mi = 0; mi < 2; mi++)
            accO[mi][ni] = __builtin_amdgcn_mfma_f32_16x16x32_bf16(pf[mi], vf, accO[mi][ni], 0, 0, 0);
        }
      }
      __builtin_amdgcn_s_setprio(0);

      if (t + 1 < ntiles) STAGE(cur ^ 1);
    }

    // epilogue: normalize and store bf16
#pragma unroll
    for (int mi = 0; mi < 2; mi++) {
      float inv[4];
#pragma unroll
      for (int r = 0; r < 4; r++) inv[r] = 1.0f / lrun[mi][r];
#pragma unroll
      for (int ni = 0; ni < 8; ni++)
#pragma unroll
        for (int r = 0; r < 4; r++) {
          int q = qwb + mi * 16 + l4 * 4 + r;
          int hd = ni * 16 + l15;
          aout[((long)b * SS + q) * 2048 + h * 128 + hd] = __float2bfloat16(accO[mi][ni][r] * inv[r]);
        }
    }
  }
#undef LOADKV
#undef STAGE
}

extern "C" void kernel_launch(void* const* d_in, const int* in_sizes, int n_in,
                              void* d_out, int out_size, void* d_ws, size_t ws_size,
                              hipStream_t stream) {
  (void)in_sizes; (void)n_in; (void)out_size; (void)ws_size;
  const float* h  = (const float*)d_in[0];
  const float* Wq = (const float*)d_in[1];
  const float* Wk = (const float*)d_in[2];
  const float* Wv = (const float*)d_in[3];
  const float* Wo = (const float*)d_in[4];
  const float* fc = (const float*)d_in[7];
  const float* fs = (const float*)d_in[8];
  const int* pos  = (const int*)d_in[9];
  float* out = (float*)d_out;

  char* ws = (char*)d_ws;
  __hip_bfloat16* hb    = (__hip_bfloat16*)(ws);                 // 33,554,432 B
  __hip_bfloat16* wqkv  = (__hip_bfloat16*)(ws + 33554432);      // 25,165,824 B
  __hip_bfloat16* wo_b  = (__hip_bfloat16*)(ws + 58720256);      //  8,388,608 B
  __hip_bfloat16* qkbuf = (__hip_bfloat16*)(ws + 67108864);      // 67,108,864 B
  __hip_bfloat16* vt    = (__hip_bfloat16*)(ws + 134217728);     // 33,554,432 B
  __hip_bfloat16* aout  = hb;  // alias: hb dead after GEMM1

  convertk<<<16384, 256, 0, stream>>>(h, hb, 4194304);
  convertk<<<4096, 256, 0, stream>>>(Wq, wqkv, 1048576);
  convertk<<<4096, 256, 0, stream>>>(Wk, wqkv + 4194304, 1048576);
  convertk<<<4096, 256, 0, stream>>>(Wv, wqkv + 8388608, 1048576);
  convertk<<<4096, 256, 0, stream>>>(Wo, wo_b, 1048576);

  // QKV projection: M=8192, N=6144, K=2048
  gemm_bt<0><<<dim3(64, 48), 256, 0, stream>>>(hb, wqkv, qkbuf, vt, nullptr, 8192, 6144, 2048);

  // RoPE on Q,K
  rope_k<<<8192, 256, 0, stream>>>(qkbuf, fc, fs, pos);

  // causal flash attention (balanced, 512 blocks)
  attn_k<<<512, 256, 0, stream>>>(qkbuf, vt, aout, pos);

  // output projection: M=8192, N=2048, K=2048 -> fp32 d_out
  gemm_bt<1><<<dim3(64, 16), 256, 0, stream>>>(aout, wo_b, nullptr, nullptr, out, 8192, 2048, 2048);
}

// Round 5
// 859.697 us; speedup vs baseline: 1.1677x; 1.1677x over previous
//
#include <hip/hip_runtime.h>
#include <hip/hip_bf16.h>

typedef __attribute__((ext_vector_type(8))) short bf16x8;
typedef __attribute__((ext_vector_type(4))) float f32x4;
typedef __attribute__((ext_vector_type(4))) unsigned short u16x4;

#define BB 4
#define SS 2048
#define DD 2048
#define HH 16
#define HDD 128
// QK buffer: [B*S][4096] bf16 (Q cols 0..2047, K cols 2048..4095), RoPE pre-applied
// Vt buffer: [B*H][128][2048] bf16 (V transposed: hd-major, s contiguous)
// Masking sentinels: finite so (masked) - (init) never yields exp2(0)=1.
#define MASKV (-30000.0f)
#define MINIT (-15000.0f)

__device__ __forceinline__ unsigned short f2bf(float f) {
  __hip_bfloat16 b = __float2bfloat16(f);
  return *reinterpret_cast<unsigned short*>(&b);
}
__device__ __forceinline__ void gl_lds16(const void* g, void* l) {
  __builtin_amdgcn_global_load_lds((const __attribute__((address_space(1))) unsigned int*)g,
                                   (__attribute__((address_space(3))) unsigned int*)l, 16, 0, 0);
}

// ---------------- fp32 -> bf16 conversion (vectorized) ----------------
__global__ __launch_bounds__(256) void convertk(const float* __restrict__ src,
                                                __hip_bfloat16* __restrict__ dst, int n4) {
  int i = blockIdx.x * 256 + threadIdx.x;
  if (i >= n4) return;
  f32x4 v = ((const f32x4*)src)[i];
  u16x4 o;
  o[0] = f2bf(v[0]); o[1] = f2bf(v[1]); o[2] = f2bf(v[2]); o[3] = f2bf(v[3]);
  ((u16x4*)dst)[i] = o;
}

// ---------------- B^T GEMM: C[m][n] = sum_k A[m][k] * Bw[n][k] ----------------
// MODE 0: epilogue -> QK buffer with fused RoPE (n<4096) or Vt (n>=4096, transposed)
// MODE 1: epilogue -> float C row-major [M][N]
template <int MODE>
__global__ __launch_bounds__(256) void gemm_bt(const __hip_bfloat16* __restrict__ A,
                                               const __hip_bfloat16* __restrict__ Bw,
                                               __hip_bfloat16* __restrict__ Cbf,
                                               __hip_bfloat16* __restrict__ Vt,
                                               float* __restrict__ Cf,
                                               const float* __restrict__ fc,
                                               const float* __restrict__ fs,
                                               const int* __restrict__ posp,
                                               int M, int N, int K) {
  __shared__ __hip_bfloat16 As[128 * 32];
  __shared__ __hip_bfloat16 Bs[128 * 32];
  const int tid = threadIdx.x;
  const int wave = tid >> 6, lane = tid & 63;
  const int l15 = lane & 15, l4 = lane >> 4;
  const int bm = blockIdx.x, bn = blockIdx.y;
  const int wr = (wave >> 1) * 64, wc = (wave & 1) * 64;

  const long arow = (long)(bm * 128 + (tid >> 2)) * K + (tid & 3) * 8;
  const long brow = (long)(bn * 128 + (tid >> 2)) * K + (tid & 3) * 8;

  f32x4 acc[4][4] = {};

  for (int k0 = 0; k0 < K; k0 += 32) {
    const __hip_bfloat16* ga = A + arow + k0;
    const __hip_bfloat16* gb = Bw + brow + k0;
    gl_lds16(ga, As + tid * 8);
    gl_lds16(ga + (long)64 * K, As + 2048 + tid * 8);
    gl_lds16(gb, Bs + tid * 8);
    gl_lds16(gb + (long)64 * K, Bs + 2048 + tid * 8);
    __syncthreads();

    bf16x8 af[4], bg[4];
#pragma unroll
    for (int i = 0; i < 4; i++) {
      af[i] = *(const bf16x8*)(As + (wr + i * 16 + l15) * 32 + l4 * 8);
      bg[i] = *(const bf16x8*)(Bs + (wc + i * 16 + l15) * 32 + l4 * 8);
    }
#pragma unroll
    for (int mi = 0; mi < 4; mi++)
#pragma unroll
      for (int nj = 0; nj < 4; nj++)
        acc[mi][nj] = __builtin_amdgcn_mfma_f32_16x16x32_bf16(af[mi], bg[nj], acc[mi][nj], 0, 0, 0);
    __syncthreads();
  }

  if (MODE == 0) {
    if (bn * 128 < 4096) {
      // Q or K region: fused RoPE (pairs along hd exchanged via shfl_xor 1), -> QK buffer
      const int pos = *posp;
#pragma unroll
      for (int mi = 0; mi < 4; mi++)
#pragma unroll
        for (int nj = 0; nj < 4; nj++) {
          int n = bn * 128 + wc + nj * 16 + l15;
          int hd = n & 127;
          int ip = hd >> 1;
          bool odd = hd & 1;
#pragma unroll
          for (int r = 0; r < 4; r++) {
            float v = acc[mi][nj][r];
            float p = __shfl_xor(v, 1, 64);
            int m = bm * 128 + wr + mi * 16 + l4 * 4 + r;
            int s = m & (SS - 1);
            float cv = fc[(long)(pos + s) * 64 + ip];
            float sv = fs[(long)(pos + s) * 64 + ip];
            float out = odd ? (p * sv + v * cv) : (v * cv - p * sv);
            Cbf[(long)m * 4096 + n] = __float2bfloat16(out);
          }
        }
    } else {
      // V region -> Vt[(b*16+h)*128+hd][s], pack 4 consecutive s
#pragma unroll
      for (int mi = 0; mi < 4; mi++)
#pragma unroll
        for (int nj = 0; nj < 4; nj++) {
          int e = bn * 128 + wc + nj * 16 + l15 - 4096;
          int hh = e >> 7, hd = e & 127;
          int m0 = bm * 128 + wr + mi * 16 + l4 * 4;
          int b = m0 >> 11, s0 = m0 & (SS - 1);
          u16x4 pk;
#pragma unroll
          for (int r = 0; r < 4; r++) pk[r] = f2bf(acc[mi][nj][r]);
          *(u16x4*)(Vt + (((long)(b * HH + hh) * 128 + hd) * SS + s0)) = pk;
        }
    }
  } else {
#pragma unroll
    for (int mi = 0; mi < 4; mi++)
#pragma unroll
      for (int nj = 0; nj < 4; nj++) {
        int n = bn * 128 + wc + nj * 16 + l15;
#pragma unroll
        for (int r = 0; r < 4; r++) {
          int m = bm * 128 + wr + mi * 16 + l4 * 4 + r;
          Cf[(long)m * N + n] = acc[mi][nj][r];
        }
      }
  }
}

// ---------------- causal flash attention ----------------
// 512 blocks (8 q-pairs x 64 bh, XCD-swizzled); block does q-tiles qp (KV ascending)
// then 15-qp (KV DESCENDING): at global step s every block of a bh reads tile s or 33-s
// -> two shared L2-resident streams. 4 waves x 32 q-rows; KVBLK=64; LDS dbuf; async
// stage split; defer-max (finite sentinels); exp2 softmax; coalesced epilogue.
__global__ __launch_bounds__(256, 2) void attn_k(const __hip_bfloat16* __restrict__ qk,
                                                 const __hip_bfloat16* __restrict__ vt,
                                                 __hip_bfloat16* __restrict__ aout,
                                                 const int* __restrict__ posp) {
  __shared__ __hip_bfloat16 Ks[2][64 * 128];   // [key][hd], XOR-swizzled
  __shared__ __hip_bfloat16 Vs[2][128 * 64];   // [hd][kv] (V^T), XOR-swizzled
  __shared__ __hip_bfloat16 Ps[4][32 * 64];    // per-wave P, XOR-swizzled
  const int pos = *posp;
  const int orig = blockIdx.x;                  // 512 blocks
  const int swz = (orig & 7) * 64 + (orig >> 3);  // XCD-contiguous
  const int qp = swz & 7, bh = swz >> 3;
  const int b = bh >> 4, h = bh & 15;
  const int tid = threadIdx.x;
  const int wave = tid >> 6, lane = tid & 63;
  const int l15 = lane & 15, l4 = lane >> 4;

  const long kbase = ((long)b * SS) * 4096 + 2048 + h * 128;
  const long vbase = ((long)bh * 128) * SS;
  const float sc2 = 0.08838834764831845f * 1.4426950408889634f;  // 1/sqrt(128)*log2(e)

  const int s_kr[4] = {(0 * 256 + tid) >> 4, (1 * 256 + tid) >> 4, (2 * 256 + tid) >> 4, (3 * 256 + tid) >> 4};
  const int s_kc = tid & 15;
  const int s_hd[4] = {(0 * 256 + tid) >> 3, (1 * 256 + tid) >> 3, (2 * 256 + tid) >> 3, (3 * 256 + tid) >> 3};
  const int s_vc = tid & 7;

  bf16x8 kreg[4], vreg[4];

#define LOADKV(T)                                                                             \
  {                                                                                           \
    const int kv0_ = (T) * 64;                                                                \
    _Pragma("unroll") for (int i = 0; i < 4; i++) {                                           \
      kreg[i] = *(const bf16x8*)(qk + kbase + (long)(kv0_ + s_kr[i]) * 4096 + s_kc * 8);      \
      vreg[i] = *(const bf16x8*)(vt + vbase + (long)s_hd[i] * SS + kv0_ + s_vc * 8);          \
    }                                                                                         \
  }

#define STAGE(BI)                                                                             \
  {                                                                                           \
    _Pragma("unroll") for (int i = 0; i < 4; i++) {                                           \
      *(bf16x8*)(Ks[BI] + ((s_kr[i] * 128 + s_kc * 8) ^ ((s_kr[i] & 7) << 3))) = kreg[i];     \
      *(bf16x8*)(Vs[BI] + ((s_hd[i] * 64 + s_vc * 8) ^ ((s_hd[i] & 7) << 3))) = vreg[i];      \
    }                                                                                         \
  }

  for (int half = 0; half < 2; ++half) {
    const int qb = half ? (15 - qp) : qp;
    const int qwb = qb * 128 + wave * 32;

    // Q fragments in registers
    bf16x8 qf[2][4];
#pragma unroll
    for (int mi = 0; mi < 2; mi++)
#pragma unroll
      for (int kk = 0; kk < 4; kk++) {
        long row = (long)b * SS + qwb + mi * 16 + l15;
        qf[mi][kk] = *(const bf16x8*)(qk + row * 4096 + h * 128 + kk * 32 + l4 * 8);
      }

    f32x4 accO[2][8] = {};
    float mrun[2][4], lrun[2][4];
#pragma unroll
    for (int mi = 0; mi < 2; mi++)
#pragma unroll
      for (int r = 0; r < 4; r++) { mrun[mi][r] = MINIT; lrun[mi][r] = 0.f; }

    int ntiles = (pos + qb * 128 + 127) / 64 + 1;
    if (ntiles > SS / 64) ntiles = SS / 64;
    // half 0: ascending t; half 1: descending (two shared streams per bh)
#define TT(t) (half ? (ntiles - 1 - (t)) : (t))

    LOADKV(TT(0));
    __syncthreads();   // protect buffers from previous half's last reads
    STAGE(0);

    for (int t = 0; t < ntiles; ++t) {
      const int kv0 = TT(t) * 64;
      const int cur = t & 1;
      if (t + 1 < ntiles) LOADKV(TT(t + 1));   // async: in flight across barrier+compute
      __syncthreads();                          // staged tile visible

      // ---- S = Q K^T ----
      f32x4 sfr[2][4] = {};
      __builtin_amdgcn_s_setprio(1);
#pragma unroll
      for (int ni = 0; ni < 4; ni++) {
        const int key = ni * 16 + l15;
        const int sw = (key & 7) << 3;
        bf16x8 kf[4];
#pragma unroll
        for (int kk = 0; kk < 4; kk++)
          kf[kk] = *(const bf16x8*)(Ks[cur] + ((key * 128 + kk * 32 + l4 * 8) ^ sw));
#pragma unroll
        for (int mi = 0; mi < 2; mi++)
#pragma unroll
          for (int kk = 0; kk < 4; kk++)
            sfr[mi][ni] = __builtin_amdgcn_mfma_f32_16x16x32_bf16(qf[mi][kk], kf[kk], sfr[mi][ni], 0, 0, 0);
      }
      __builtin_amdgcn_s_setprio(0);

      // ---- scale (log2 domain) + causal mask (finite sentinel) ----
      const bool needmask = (kv0 + 63) > (pos + qb * 128);
#pragma unroll
      for (int mi = 0; mi < 2; mi++)
#pragma unroll
        for (int ni = 0; ni < 4; ni++)
#pragma unroll
          for (int r = 0; r < 4; r++) {
            float v = sfr[mi][ni][r] * sc2;
            if (needmask) {
              int key = kv0 + ni * 16 + l15;
              int q = qwb + mi * 16 + l4 * 4 + r;
              if (key > pos + q) v = MASKV;
            }
            sfr[mi][ni][r] = v;
          }

      // ---- online softmax with defer-max ----
#pragma unroll
      for (int mi = 0; mi < 2; mi++) {
        f32x4 mx = sfr[mi][0];
#pragma unroll
        for (int ni = 1; ni < 4; ni++)
#pragma unroll
          for (int r = 0; r < 4; r++) mx[r] = fmaxf(mx[r], sfr[mi][ni][r]);
#pragma unroll
        for (int d = 1; d < 16; d <<= 1)
#pragma unroll
          for (int r = 0; r < 4; r++) mx[r] = fmaxf(mx[r], __shfl_xor(mx[r], d, 64));

        float growth = mx[0] - mrun[mi][0];
#pragma unroll
        for (int r = 1; r < 4; r++) growth = fmaxf(growth, mx[r] - mrun[mi][r]);
        if (!__all(growth <= 11.0f)) {
          float scal[4];
#pragma unroll
          for (int r = 0; r < 4; r++) {
            float mn = fmaxf(mrun[mi][r], mx[r]);
            scal[r] = exp2f(mrun[mi][r] - mn);
            mrun[mi][r] = mn;
            lrun[mi][r] *= scal[r];
          }
#pragma unroll
          for (int ni = 0; ni < 8; ni++)
#pragma unroll
            for (int r = 0; r < 4; r++) accO[mi][ni][r] *= scal[r];
        }

        f32x4 rs = {0.f, 0.f, 0.f, 0.f};
#pragma unroll
        for (int ni = 0; ni < 4; ni++)
#pragma unroll
          for (int r = 0; r < 4; r++) {
            float p = exp2f(sfr[mi][ni][r] - mrun[mi][r]);
            rs[r] += p;
            int prow = mi * 16 + l4 * 4 + r;
            Ps[wave][(prow * 64 + ni * 16 + l15) ^ ((prow & 7) << 3)] = __float2bfloat16(p);
          }
#pragma unroll
        for (int d = 1; d < 16; d <<= 1)
#pragma unroll
          for (int r = 0; r < 4; r++) rs[r] += __shfl_xor(rs[r], d, 64);
#pragma unroll
        for (int r = 0; r < 4; r++) lrun[mi][r] += rs[r];
      }

      // ---- O += P * V ----
      __builtin_amdgcn_s_setprio(1);
#pragma unroll
      for (int kk = 0; kk < 2; kk++) {
        bf16x8 pf[2];
#pragma unroll
        for (int mi = 0; mi < 2; mi++) {
          int prow = mi * 16 + l15;
          pf[mi] = *(const bf16x8*)(Ps[wave] + ((prow * 64 + kk * 32 + l4 * 8) ^ ((prow & 7) << 3)));
        }
#pragma unroll
        for (int ni = 0; ni < 8; ni++) {
          int hd = ni * 16 + l15;
          bf16x8 vf = *(const bf16x8*)(Vs[cur] + ((hd * 64 + kk * 32 + l4 * 8) ^ ((hd & 7) << 3)));
#pragma unroll
          for (int mi = 0; mi < 2; mi++)
            accO[mi][ni] = __builtin_amdgcn_mfma_f32_16x16x32_bf16(pf[mi], vf, accO[mi][ni], 0, 0, 0);
        }
      }
      __builtin_amdgcn_s_setprio(0);

      if (t + 1 < ntiles) STAGE(cur ^ 1);
    }
#undef TT

    // ---- epilogue: normalize, LDS-transpose, coalesced 16B stores ----
    __syncthreads();  // all waves done reading Ks/Vs/Ps
    __hip_bfloat16* E = &Ks[0][0] + wave * 4096;  // 32 rows x 128 cols bf16 = 8KB/wave
#pragma unroll
    for (int mi = 0; mi < 2; mi++) {
      float inv[4];
#pragma unroll
      for (int r = 0; r < 4; r++) inv[r] = 1.0f / lrun[mi][r];
#pragma unroll
      for (int ni = 0; ni < 8; ni++)
#pragma unroll
        for (int r = 0; r < 4; r++) {
          int row = mi * 16 + l4 * 4 + r;
          E[(row * 128 + ni * 16 + l15) ^ ((row & 7) << 3)] =
              __float2bfloat16(accO[mi][ni][r] * inv[r]);
        }
    }
    const long gb = ((long)b * SS + qwb) * 2048 + h * 128;
    // 32 rows x 128 cols per wave: 8 iters x 64 lanes x 8 elems = 4096
#pragma unroll
    for (int j = 0; j < 8; j++) {
      int row = j * 4 + (lane >> 4);
      int c8 = (lane & 15) * 8;
      bf16x8 v = *(const bf16x8*)(E + ((row * 128 + c8) ^ ((row & 7) << 3)));
      *(bf16x8*)(aout + gb + (long)row * 2048 + c8) = v;
    }
  }
#undef LOADKV
#undef STAGE
}

extern "C" void kernel_launch(void* const* d_in, const int* in_sizes, int n_in,
                              void* d_out, int out_size, void* d_ws, size_t ws_size,
                              hipStream_t stream) {
  (void)in_sizes; (void)n_in; (void)out_size; (void)ws_size;
  const float* h  = (const float*)d_in[0];
  const float* Wq = (const float*)d_in[1];
  const float* Wk = (const float*)d_in[2];
  const float* Wv = (const float*)d_in[3];
  const float* Wo = (const float*)d_in[4];
  const float* fc = (const float*)d_in[7];
  const float* fs = (const float*)d_in[8];
  const int* pos  = (const int*)d_in[9];
  float* out = (float*)d_out;

  char* ws = (char*)d_ws;
  __hip_bfloat16* hb    = (__hip_bfloat16*)(ws);                 // 33,554,432 B
  __hip_bfloat16* wqkv  = (__hip_bfloat16*)(ws + 33554432);      // 25,165,824 B
  __hip_bfloat16* wo_b  = (__hip_bfloat16*)(ws + 58720256);      //  8,388,608 B
  __hip_bfloat16* qkbuf = (__hip_bfloat16*)(ws + 67108864);      // 67,108,864 B
  __hip_bfloat16* vt    = (__hip_bfloat16*)(ws + 134217728);     // 33,554,432 B
  __hip_bfloat16* aout  = hb;  // alias: hb dead after GEMM1

  convertk<<<16384, 256, 0, stream>>>(h, hb, 4194304);
  convertk<<<4096, 256, 0, stream>>>(Wq, wqkv, 1048576);
  convertk<<<4096, 256, 0, stream>>>(Wk, wqkv + 4194304, 1048576);
  convertk<<<4096, 256, 0, stream>>>(Wv, wqkv + 8388608, 1048576);
  convertk<<<4096, 256, 0, stream>>>(Wo, wo_b, 1048576);

  // QKV projection + fused RoPE: M=8192, N=6144, K=2048
  gemm_bt<0><<<dim3(64, 48), 256, 0, stream>>>(hb, wqkv, qkbuf, vt, nullptr, fc, fs, pos,
                                               8192, 6144, 2048);

  // causal flash attention (balanced, two-stream L2-local, 512 blocks)
  attn_k<<<512, 256, 0, stream>>>(qkbuf, vt, aout, pos);

  // output projection: M=8192, N=2048, K=2048 -> fp32 d_out
  gemm_bt<1><<<dim3(64, 16), 256, 0, stream>>>(aout, wo_b, nullptr, nullptr, out, nullptr,
                                               nullptr, nullptr, 8192, 2048, 2048);
}